// Round 7
// baseline (195.645 us; speedup 1.0000x reference)
//
#include <hip/hip_runtime.h>
#include <math.h>

// Problem constants
#define BATCH 4
#define HH 56
#define WW 56
#define DMODEL 256
#define NHEADS 8
#define HD 32
#define NNB 49               // 7x7 neighborhood
#define NTOK (BATCH*HH*WW)   // 12544

#define HALO 22              // 16 + 2*3
#define NHTOK (HALO*HALO)    // 484
#define KV_PAD 40

typedef __attribute__((ext_vector_type(8))) short s16x8;
typedef __attribute__((ext_vector_type(4))) float f32x4;
typedef __attribute__((ext_vector_type(2))) float f32x2;

__device__ inline unsigned short f2b(float f) {
    union { float f; unsigned int u; } v; v.f = f;
    unsigned int r = v.u + 0x7FFF + ((v.u >> 16) & 1);  // RNE
    return (unsigned short)(r >> 16);
}
__device__ inline float b2f(unsigned short u) {
    union { float f; unsigned int u; } v; v.u = ((unsigned int)u) << 16;
    return v.f;
}

// unpack 2 packed bf16 (one u32) -> f32x2 {elem0, elem1}; 2 VALU ops
__device__ __forceinline__ f32x2 unpk(unsigned int u) {
    union { unsigned int u; float f; } lo, hi;
    lo.u = u << 16;
    hi.u = u & 0xffff0000u;
    return f32x2{lo.f, hi.f};
}

// packed fma -> v_pk_fma_f32 (VOP3P); 1 issue for 2 lanes of math
__device__ __forceinline__ f32x2 pk_fma(f32x2 a, f32x2 b, f32x2 c) {
#if __has_builtin(__builtin_elementwise_fma)
    return __builtin_elementwise_fma(a, b, c);
#else
    return f32x2{fmaf(a.x, b.x, c.x), fmaf(a.y, b.y, c.y)};
#endif
}

// async 16B/lane global->LDS copy; lds base wave-uniform, lane i -> base+i*16
__device__ __forceinline__ void async16(const unsigned short* g, unsigned short* l) {
    __builtin_amdgcn_global_load_lds(
        (const __attribute__((address_space(1))) unsigned int*)g,
        (__attribute__((address_space(3))) unsigned int*)l, 16, 0, 0);
}

// counted-vmcnt fences (T4). Memory clobber keeps LDS reads from hoisting
// above the wait; sched_barrier pins the boundary (rule #18).
#define WAITV(N) { asm volatile("s_waitcnt vmcnt(" #N ")" ::: "memory"); }
#define BAR()    { __builtin_amdgcn_s_barrier(); __builtin_amdgcn_sched_barrier(0); }

// ---------------------------------------------------------------------------
// prep: cast x to bf16 + cast+transpose weights to [N][K] bf16 via LDS-tiled
// 64x64 transpose (R2).
// ---------------------------------------------------------------------------
#define XCAST_BLOCKS 1568    // NTOK*256/8/256

__device__ __forceinline__ void transpose_tile(
    const float* __restrict__ src, unsigned short* __restrict__ dst,
    int K, int N, int kt, int nt, int tid, float* lds /*64x65*/)
{
    const int k0 = kt * 64, n0 = nt * 64;
    #pragma unroll
    for (int p = 0; p < 4; ++p) {               // read 16 k-rows x 64 n each
        const int r  = p * 16 + (tid >> 4);
        const int c4 = (tid & 15) * 4;
        const float4 v = *(const float4*)(src + (size_t)(k0 + r) * N + n0 + c4);
        lds[r * 65 + c4 + 0] = v.x; lds[r * 65 + c4 + 1] = v.y;
        lds[r * 65 + c4 + 2] = v.z; lds[r * 65 + c4 + 3] = v.w;
    }
    __syncthreads();
    #pragma unroll
    for (int p = 0; p < 4; ++p) {               // write 16 n-rows x 64 k each
        const int c  = p * 16 + (tid >> 4);
        const int k4 = (tid & 15) * 4;
        ushort4 o;
        o.x = f2b(lds[(k4 + 0) * 65 + c]);
        o.y = f2b(lds[(k4 + 1) * 65 + c]);
        o.z = f2b(lds[(k4 + 2) * 65 + c]);
        o.w = f2b(lds[(k4 + 3) * 65 + c]);
        *(ushort4*)(dst + (size_t)(n0 + c) * K + k0 + k4) = o;
    }
}

__global__ __launch_bounds__(256)
void prep_kernel(const float* __restrict__ x,
                 const float* __restrict__ Wq, const float* __restrict__ Wp,
                 const float* __restrict__ W1, const float* __restrict__ W2,
                 unsigned short* __restrict__ xb,
                 unsigned short* __restrict__ Wqb, unsigned short* __restrict__ Wpb,
                 unsigned short* __restrict__ W1b, unsigned short* __restrict__ W2b)
{
    __shared__ float lds[64 * 65];
    const int tid = threadIdx.x;
    if (blockIdx.x < XCAST_BLOCKS) {
        const int i = blockIdx.x * 256 + tid;   // 8 floats each
        const float4* xp = (const float4*)x + (size_t)i * 2;
        const float4 a = xp[0], b = xp[1];
        s16x8 o;
        o[0] = (short)f2b(a.x); o[1] = (short)f2b(a.y);
        o[2] = (short)f2b(a.z); o[3] = (short)f2b(a.w);
        o[4] = (short)f2b(b.x); o[5] = (short)f2b(b.y);
        o[6] = (short)f2b(b.z); o[7] = (short)f2b(b.w);
        *((s16x8*)xb + i) = o;
        return;
    }
    int wb = blockIdx.x - XCAST_BLOCKS;
    if (wb < 48) {                 // W_qkv: K=256, N=768 -> 4x12 tiles
        transpose_tile(Wq, Wqb, 256, 768, wb & 3, wb >> 2, tid, lds);
    } else if ((wb -= 48) < 16) {  // W_proj: K=256, N=256 -> 4x4
        transpose_tile(Wp, Wpb, 256, 256, wb & 3, wb >> 2, tid, lds);
    } else if ((wb -= 16) < 64) {  // W1: K=256, N=1024 -> 4x16
        transpose_tile(W1, W1b, 256, 1024, wb & 3, wb >> 2, tid, lds);
    } else {                       // W2: K=1024, N=256 -> 16x4
        wb -= 64;
        transpose_tile(W2, W2b, 1024, 256, wb & 15, wb >> 4, tid, lds);
    }
}

// ---------------------------------------------------------------------------
// bf16 MFMA GEMM, 128x128 tile, 4 waves; XOR-swizzled LDS, XCD chunking,
// LDS-bounce epilogue (R4); counted-vmcnt pipeline (R5).
// ---------------------------------------------------------------------------
__global__ __launch_bounds__(256)
void gemm_k(const unsigned short* __restrict__ Ab,
            const unsigned short* __restrict__ Bt, const float* __restrict__ bias,
            unsigned short* __restrict__ outb,
            int N, int K, int relu)
{
    __shared__ unsigned short As[2][128 * 64];   // 32 KB (reused as Cs in epilogue)
    __shared__ unsigned short Bs[2][128 * 64];   // 32 KB

    const int tid = threadIdx.x;

    // m204 bijective XCD chunk swizzle; desired ordering d is bm-major.
    const int nwg = gridDim.x;
    const int q8 = nwg >> 3, r8 = nwg & 7;
    const int xcd = blockIdx.x & 7, pos = blockIdx.x >> 3;
    const int d = (xcd < r8 ? xcd * (q8 + 1) : r8 * (q8 + 1) + (xcd - r8) * q8) + pos;
    const int nbx = N >> 7;                      // 128-wide col tiles
    const int bm = (d / nbx) * 128, bn = (d % nbx) * 128;

    const int wid = tid >> 6, lane = tid & 63;
    const int wm = (wid >> 1) * 64, wn = (wid & 1) * 64;
    const int row16 = lane & 15, quad = lane >> 4;
    const int crow = lane >> 3;
    const int ckS = ((lane & 7) ^ crow) * 8;     // XOR-swizzled source k-block

    f32x4 acc[4][4] = {};

    auto stage = [&](int buf, int k0) {          // 8 loads per wave
        #pragma unroll
        for (int c = 0; c < 4; ++c) {
            const int ch = wid * 4 + c;
            async16(Ab + (size_t)(bm + ch * 8 + crow) * K + k0 + ckS, As[buf] + ch * 512);
        }
        #pragma unroll
        for (int c = 0; c < 4; ++c) {
            const int ch = wid * 4 + c;
            async16(Bt + (size_t)(bn + ch * 8 + crow) * K + k0 + ckS, Bs[buf] + ch * 512);
        }
    };
    auto compute = [&](int buf) {
        #pragma unroll
        for (int kc = 0; kc < 2; ++kc) {
            s16x8 af[4], bf[4];
            #pragma unroll
            for (int i = 0; i < 4; ++i)
                af[i] = *(const s16x8*)(As[buf] + (wm + i * 16 + row16) * 64
                                        + (((kc * 4 + quad) ^ (row16 & 7)) * 8));
            #pragma unroll
            for (int j = 0; j < 4; ++j)
                bf[j] = *(const s16x8*)(Bs[buf] + (wn + j * 16 + row16) * 64
                                        + (((kc * 4 + quad) ^ (row16 & 7)) * 8));
            #pragma unroll
            for (int i = 0; i < 4; ++i)
                #pragma unroll
                for (int j = 0; j < 4; ++j)
                    acc[i][j] = __builtin_amdgcn_mfma_f32_16x16x32_bf16(af[i], bf[j], acc[i][j], 0, 0, 0);
        }
    };

    stage(0, 0);
    stage(1, 64);
    const int nsteps = K >> 6;                   // 4 (K=256)
    for (int s = 0; s < nsteps; ++s) {
        const int buf = s & 1;
        if (s == nsteps - 1) WAITV(0) else WAITV(8)     // own buf's 8 loads done
        BAR()                                           // all waves' loads landed
        compute(buf);
        BAR()                                           // all waves done reading buf
        if (s + 2 < nsteps) stage(buf, (s + 2) << 6);
    }

    // ---- epilogue: bias (+relu) -> bf16 via LDS bounce, coalesced stores
    unsigned short* Cs = (unsigned short*)As;    // 128x128 bf16 = 32 KB
    #pragma unroll
    for (int j = 0; j < 4; ++j) {
        const int col = wn + j * 16 + row16;
        const float bb = bias[bn + col];
        #pragma unroll
        for (int i = 0; i < 4; ++i) {
            const int rr = wm + i * 16 + quad * 4;
            #pragma unroll
            for (int reg = 0; reg < 4; ++reg) {
                float v = acc[i][j][reg] + bb;
                if (relu) v = fmaxf(v, 0.f);
                Cs[(rr + reg) * 128 + col] = f2b(v);
            }
        }
    }
    __syncthreads();
    #pragma unroll
    for (int p = 0; p < 8; ++p) {
        const int s = p * 256 + tid;             // 2048 x 16B chunks
        const int rr = s >> 4, cb = (s & 15) * 8;
        *(s16x8*)(outb + (size_t)(bm + rr) * N + bn + cb) = *(const s16x8*)(Cs + rr * 128 + cb);
    }
}

// ---------------------------------------------------------------------------
// Fused GEMM (N=256 full-row tile) + residual add + LayerNorm.
// BM=64, 512 threads (8 waves, 2m x 4n), XOR-swizzled LDS, counted vmcnt.
// ---------------------------------------------------------------------------
__global__ __launch_bounds__(512)
void gemm_ln(const unsigned short* __restrict__ Ab, const unsigned short* __restrict__ Bt,
             const float* __restrict__ bias, const float* __restrict__ resid,
             const float* __restrict__ g, const float* __restrict__ beta,
             float* __restrict__ outf, unsigned short* __restrict__ outb, int K)
{
    __shared__ unsigned short As[2][64 * 64];    // 16 KB (buf0 reused for LN reduce)
    __shared__ unsigned short Bs[2][256 * 64];   // 64 KB

    const int tid = threadIdx.x;
    const int bm = blockIdx.x * 64;
    const int wid = tid >> 6, lane = tid & 63;
    const int wm = (wid >> 2) * 32, wn = (wid & 3) * 64;
    const int wc = wid & 3;
    const int row16 = lane & 15, quad = lane >> 4;
    const int crow = lane >> 3;
    const int ckS = ((lane & 7) ^ crow) * 8;     // XOR-swizzled source k-block

    f32x4 acc[2][4] = {};

    auto stage = [&](int buf, int k0) {          // 5 loads per wave
        #pragma unroll
        for (int c = 0; c < 5; ++c) {
            const int ch = wid * 5 + c;
            if (ch < 8) {
                async16(Ab + (size_t)(bm + ch * 8 + crow) * K + k0 + ckS, As[buf] + ch * 512);
            } else {
                const int bc = ch - 8;
                async16(Bt + (size_t)(bc * 8 + crow) * K + k0 + ckS, Bs[buf] + bc * 512);
            }
        }
    };
    auto compute = [&](int buf) {
        #pragma unroll
        for (int kc = 0; kc < 2; ++kc) {
            s16x8 af[2], bf[4];
            #pragma unroll
            for (int i = 0; i < 2; ++i)
                af[i] = *(const s16x8*)(As[buf] + (wm + i * 16 + row16) * 64
                                        + (((kc * 4 + quad) ^ (row16 & 7)) * 8));
            #pragma unroll
            for (int j = 0; j < 4; ++j)
                bf[j] = *(const s16x8*)(Bs[buf] + (wn + j * 16 + row16) * 64
                                        + (((kc * 4 + quad) ^ (row16 & 7)) * 8));
            #pragma unroll
            for (int i = 0; i < 2; ++i)
                #pragma unroll
                for (int j = 0; j < 4; ++j)
                    acc[i][j] = __builtin_amdgcn_mfma_f32_16x16x32_bf16(af[i], bf[j], acc[i][j], 0, 0, 0);
        }
    };

    stage(0, 0);
    stage(1, 64);
    const int nsteps = K >> 6;
    for (int s = 0; s < nsteps; ++s) {
        const int buf = s & 1;
        if (s == nsteps - 1) WAITV(0) else WAITV(5)
        BAR()
        compute(buf);
        BAR()
        if (s + 2 < nsteps) stage(buf, (s + 2) << 6);
    }

    // ---- epilogue: bias + residual, in-register
    float bb[4], gv[4], bev[4];
    #pragma unroll
    for (int j = 0; j < 4; ++j) {
        const int col = wn + j * 16 + row16;
        bb[j] = bias[col]; gv[j] = g[col]; bev[j] = beta[col];
    }
    #pragma unroll
    for (int i = 0; i < 2; ++i) {
        #pragma unroll
        for (int reg = 0; reg < 4; ++reg) {
            const size_t rb = (size_t)(bm + wm + i * 16 + quad * 4 + reg) * 256;
            #pragma unroll
            for (int j = 0; j < 4; ++j)
                acc[i][j][reg] += bb[j] + resid[rb + wn + j * 16 + row16];
        }
    }

    // ---- per-row sum / sumsq: reduce across row16 (16 lanes), then LDS
    float* red = (float*)As[0];           // [64 rows][4 col-waves][2]
    #pragma unroll
    for (int i = 0; i < 2; ++i) {
        #pragma unroll
        for (int reg = 0; reg < 4; ++reg) {
            float s1 = 0.f, s2 = 0.f;
            #pragma unroll
            for (int j = 0; j < 4; ++j) {
                const float t = acc[i][j][reg];
                s1 += t; s2 += t * t;
            }
            #pragma unroll
            for (int o = 1; o < 16; o <<= 1) {
                s1 += __shfl_xor(s1, o, 64);
                s2 += __shfl_xor(s2, o, 64);
            }
            if (row16 == 0) {
                const int lrow = wm + i * 16 + quad * 4 + reg;
                red[lrow * 8 + wc * 2]     = s1;
                red[lrow * 8 + wc * 2 + 1] = s2;
            }
        }
    }
    __syncthreads();
    float* stats = red + 512;             // [64][2] = m, invstd
    if (tid < 64) {
        const float S1 = red[tid*8] + red[tid*8+2] + red[tid*8+4] + red[tid*8+6];
        const float S2 = red[tid*8+1] + red[tid*8+3] + red[tid*8+5] + red[tid*8+7];
        const float m = S1 * (1.0f / 256.0f);
        const float var = S2 * (1.0f / 256.0f) - m * m;
        stats[tid * 2]     = m;
        stats[tid * 2 + 1] = rsqrtf(var + 1e-5f);
    }
    __syncthreads();

    // ---- normalize + store
    #pragma unroll
    for (int i = 0; i < 2; ++i) {
        #pragma unroll
        for (int reg = 0; reg < 4; ++reg) {
            const int lrow = wm + i * 16 + quad * 4 + reg;
            const float m = stats[lrow * 2], r = stats[lrow * 2 + 1];
            const size_t rb = (size_t)(bm + lrow) * 256;
            #pragma unroll
            for (int j = 0; j < 4; ++j) {
                const int col = wn + j * 16 + row16;
                const float o = (acc[i][j][reg] - m) * r * gv[j] + bev[j];
                outf[rb + col] = o;
                if (outb) outb[rb + col] = f2b(o);
            }
        }
    }
}

// ---------------------------------------------------------------------------
// Tiled neighborhood attention. R7: V is NOT staged in LDS — the per-tile V
// halo (31 KB) is L1/L2-resident with heavy cross-lane & cross-j line reuse,
// so staging it was pure overhead (m169 precedent). Only K stays in LDS
// (tight QK inner loop). LDS 77 -> 39 KB => 3 blocks/CU (launch_bounds 256,3;
// not 4, to keep VGPR <= ~168 and avoid spill).
// ---------------------------------------------------------------------------
__global__ __launch_bounds__(256, 3)
void natt_kernel(const unsigned short* __restrict__ qkvb, unsigned short* __restrict__ att)
{
    const int blk  = blockIdx.x;          // 4*16*8 = 512
    const int head = blk & 7;
    const int t2   = blk >> 3;
    const int tile = t2 & 15;
    const int b    = t2 >> 4;
    const int r0 = (tile >> 2) * 16, c0 = (tile & 3) * 16;
    const int hs = min(max(r0 - 3, 0), 34);
    const int ws = min(max(c0 - 3, 0), 34);

    __shared__ unsigned short Ks[NHTOK * KV_PAD];   // 38.7 KB

    const int tid = threadIdx.x;

    #pragma unroll
    for (int it = 0; it < 8; ++it) {
        const int t = it * 64 + (tid >> 2);
        if (t < NHTOK) {
            const int hr = t / HALO, hc = t - hr * HALO;
            const size_t rb = ((size_t)((b * 56 + hs + hr) * 56 + (ws + hc))) * 768;
            const int d8 = (tid & 3) * 8;
            *(s16x8*)(Ks + t * KV_PAD + d8) = *(const s16x8*)(qkvb + rb + 256 + head * 32 + d8);
        }
    }

    const int qh = min(r0 + (tid >> 4), 55);
    const int qw = min(c0 + (tid & 15), 55);
    const int tok = (b * 56 + qh) * 56 + qw;
    const int ro = min(max(qh - 3, 0), 49) - hs;
    const int co = min(max(qw - 3, 0), 49) - ws;
    const int nh0 = hs + ro;                    // first neighbor row (abs)
    const int nw0 = ws + co;                    // first neighbor col (abs)

    f32x2 qf[16];
    {
        const unsigned int* qp = (const unsigned int*)(qkvb + (size_t)tok * 768 + head * 32);
        #pragma unroll
        for (int p = 0; p < 16; ++p)
            qf[p] = unpk(qp[p]) * 0.17677669529663687f;
    }
    __syncthreads();

    f32x2 acc[16] = {};
    float sum = 0.f;
    for (int i = 0; i < 7; ++i) {
        const int trow = (ro + i) * HALO + co;
        // V row base for this neighbor-row, direct from global (L1/L2)
        const unsigned int* vrow = (const unsigned int*)(
            qkvb + ((size_t)((b * 56 + nh0 + i) * 56 + nw0)) * 768 + 512 + head * 32);
        #pragma unroll
        for (int j = 0; j < 7; ++j) {
            const unsigned int* kp = (const unsigned int*)(Ks + (trow + j) * KV_PAD);
            const unsigned int* vp = vrow + j * 384;     // 768 shorts = 384 uints
            const uint4 ka = *(const uint4*)(kp);
            const uint4 kb = *(const uint4*)(kp + 4);
            const uint4 kc = *(const uint4*)(kp + 8);
            const uint4 kd = *(const uint4*)(kp + 12);
            const uint4 va = *(const uint4*)(vp);
            const uint4 vb = *(const uint4*)(vp + 4);
            const uint4 vc = *(const uint4*)(vp + 8);
            const uint4 vd = *(const uint4*)(vp + 12);
            f32x2 sa = {0.f, 0.f}, sb = {0.f, 0.f};
            sa = pk_fma(qf[0],  unpk(ka.x), sa);  sb = pk_fma(qf[1],  unpk(ka.y), sb);
            sa = pk_fma(qf[2],  unpk(ka.z), sa);  sb = pk_fma(qf[3],  unpk(ka.w), sb);
            sa = pk_fma(qf[4],  unpk(kb.x), sa);  sb = pk_fma(qf[5],  unpk(kb.y), sb);
            sa = pk_fma(qf[6],  unpk(kb.z), sa);  sb = pk_fma(qf[7],  unpk(kb.w), sb);
            sa = pk_fma(qf[8],  unpk(kc.x), sa);  sb = pk_fma(qf[9],  unpk(kc.y), sb);
            sa = pk_fma(qf[10], unpk(kc.z), sa);  sb = pk_fma(qf[11], unpk(kc.w), sb);
            sa = pk_fma(qf[12], unpk(kd.x), sa);  sb = pk_fma(qf[13], unpk(kd.y), sb);
            sa = pk_fma(qf[14], unpk(kd.z), sa);  sb = pk_fma(qf[15], unpk(kd.w), sb);
            const float p = __expf(sa.x + sa.y + sb.x + sb.y);
            sum += p;
            const f32x2 pv = {p, p};
            acc[0]  = pk_fma(pv, unpk(va.x), acc[0]);
            acc[1]  = pk_fma(pv, unpk(va.y), acc[1]);
            acc[2]  = pk_fma(pv, unpk(va.z), acc[2]);
            acc[3]  = pk_fma(pv, unpk(va.w), acc[3]);
            acc[4]  = pk_fma(pv, unpk(vb.x), acc[4]);
            acc[5]  = pk_fma(pv, unpk(vb.y), acc[5]);
            acc[6]  = pk_fma(pv, unpk(vb.z), acc[6]);
            acc[7]  = pk_fma(pv, unpk(vb.w), acc[7]);
            acc[8]  = pk_fma(pv, unpk(vc.x), acc[8]);
            acc[9]  = pk_fma(pv, unpk(vc.y), acc[9]);
            acc[10] = pk_fma(pv, unpk(vc.z), acc[10]);
            acc[11] = pk_fma(pv, unpk(vc.w), acc[11]);
            acc[12] = pk_fma(pv, unpk(vd.x), acc[12]);
            acc[13] = pk_fma(pv, unpk(vd.y), acc[13]);
            acc[14] = pk_fma(pv, unpk(vd.z), acc[14]);
            acc[15] = pk_fma(pv, unpk(vd.w), acc[15]);
        }
    }
    const float inv = 1.0f / sum;

    unsigned short* op = att + (size_t)tok * DMODEL + head * 32;
    #pragma unroll
    for (int d4 = 0; d4 < 8; ++d4) {
        ushort4 o;
        o.x = f2b(acc[d4 * 2].x     * inv);
        o.y = f2b(acc[d4 * 2].y     * inv);
        o.z = f2b(acc[d4 * 2 + 1].x * inv);
        o.w = f2b(acc[d4 * 2 + 1].y * inv);
        *(ushort4*)(op + d4 * 4) = o;
    }
}

// ---------------------------------------------------------------------------
extern "C" void kernel_launch(void* const* d_in, const int* in_sizes, int n_in,
                              void* d_out, int out_size, void* d_ws, size_t ws_size,
                              hipStream_t stream)
{
    const float* x      = (const float*)d_in[0];
    const float* W_qkv  = (const float*)d_in[1];
    const float* b_qkv  = (const float*)d_in[2];
    const float* W_proj = (const float*)d_in[3];
    const float* b_proj = (const float*)d_in[4];
    const float* W1     = (const float*)d_in[5];
    const float* b1     = (const float*)d_in[6];
    const float* W2     = (const float*)d_in[7];
    const float* b2     = (const float*)d_in[8];
    const float* g1     = (const float*)d_in[9];
    const float* be1    = (const float*)d_in[10];
    const float* g2     = (const float*)d_in[11];
    const float* be2    = (const float*)d_in[12];
    float* out = (float*)d_out;

    char* ws = (char*)d_ws;
    const int M = NTOK;  // 12544

    unsigned short* qkvb = (unsigned short*)ws;                     // [M][768] bf16
    unsigned short* h    = (unsigned short*)ws;                     // [M][1024] bf16 (after qkvb dead)
    unsigned short* attb = (unsigned short*)(ws + 38535168);        // [M][256] bf16
    float*          xn   = (float*)(ws + 57802752);                 // [M][256] f32
    unsigned short* xnb  = (unsigned short*)(ws + 70647808);        // [M][256] bf16
    unsigned short* Wqb  = (unsigned short*)(ws + 77070336);
    unsigned short* Wpb  = Wqb + 196608;
    unsigned short* W1b  = Wpb + 65536;
    unsigned short* W2b  = W1b + 262144;
    unsigned short* xb   = (unsigned short*)(ws + 78643200);        // [M][256] bf16

    dim3 blk(256);

    // 0) cast x to bf16 + cast/transpose weights to bf16 (tiled transpose)
    prep_kernel<<<dim3(XCAST_BLOCKS + 48 + 16 + 64 + 64), blk, 0, stream>>>(
        x, W_qkv, W_proj, W1, W2, xb, Wqb, Wpb, W1b, W2b);

    // 1) qkvb = bf16(xb @ W_qkv + b_qkv)   (588 blocks, XCD-chunked)
    gemm_k<<<dim3(6 * 98), blk, 0, stream>>>(xb, Wqb, b_qkv, qkvb, 768, 256, 0);

    // 2) tiled neighborhood attention -> attb  (V direct from L1/L2)
    natt_kernel<<<dim3(512), blk, 0, stream>>>(qkvb, attb);

    // 3+4) xn = LN(x + attb @ W_proj + b_proj)  (f32 + bf16), fused
    gemm_ln<<<dim3(M / 64), dim3(512), 0, stream>>>(attb, Wpb, b_proj, x, g1, be1, xn, xnb, 256);

    // 5) h = relu(xnb @ W1 + b1)  (bf16, 784 blocks, XCD-chunked)
    gemm_k<<<dim3(8 * 98), blk, 0, stream>>>(xnb, W1b, b1, h, 1024, 256, 1);

    // 6+7) out = LN(xn + h @ W2 + b2), fused
    gemm_ln<<<dim3(M / 64), dim3(512), 0, stream>>>(h, W2b, b2, xn, g2, be2, out, nullptr, 1024);
}

// Round 8
// 175.272 us; speedup vs baseline: 1.1162x; 1.1162x over previous
//
#include <hip/hip_runtime.h>
#include <math.h>

// Problem constants
#define BATCH 4
#define HH 56
#define WW 56
#define DMODEL 256
#define NHEADS 8
#define HD 32
#define NNB 49               // 7x7 neighborhood
#define NTOK (BATCH*HH*WW)   // 12544

#define HALO 22              // 16 + 2*3
#define NHTOK (HALO*HALO)    // 484
#define KV_PAD 40

typedef __attribute__((ext_vector_type(8))) short s16x8;
typedef __attribute__((ext_vector_type(4))) float f32x4;
typedef __attribute__((ext_vector_type(2))) float f32x2;

__device__ inline unsigned short f2b(float f) {
    union { float f; unsigned int u; } v; v.f = f;
    unsigned int r = v.u + 0x7FFF + ((v.u >> 16) & 1);  // RNE
    return (unsigned short)(r >> 16);
}
__device__ inline float b2f(unsigned short u) {
    union { float f; unsigned int u; } v; v.u = ((unsigned int)u) << 16;
    return v.f;
}

// unpack 2 packed bf16 (one u32) -> f32x2 {elem0, elem1}; 2 VALU ops
__device__ __forceinline__ f32x2 unpk(unsigned int u) {
    union { unsigned int u; float f; } lo, hi;
    lo.u = u << 16;
    hi.u = u & 0xffff0000u;
    return f32x2{lo.f, hi.f};
}

// packed fma -> v_pk_fma_f32 (VOP3P); 1 issue for 2 lanes of math
__device__ __forceinline__ f32x2 pk_fma(f32x2 a, f32x2 b, f32x2 c) {
#if __has_builtin(__builtin_elementwise_fma)
    return __builtin_elementwise_fma(a, b, c);
#else
    return f32x2{fmaf(a.x, b.x, c.x), fmaf(a.y, b.y, c.y)};
#endif
}

// async 16B/lane global->LDS copy; lds base wave-uniform, lane i -> base+i*16
__device__ __forceinline__ void async16(const unsigned short* g, unsigned short* l) {
    __builtin_amdgcn_global_load_lds(
        (const __attribute__((address_space(1))) unsigned int*)g,
        (__attribute__((address_space(3))) unsigned int*)l, 16, 0, 0);
}

// counted-vmcnt fences (T4). Memory clobber keeps LDS reads from hoisting
// above the wait; sched_barrier pins the boundary (rule #18).
#define WAITV(N) { asm volatile("s_waitcnt vmcnt(" #N ")" ::: "memory"); }
#define BAR()    { __builtin_amdgcn_s_barrier(); __builtin_amdgcn_sched_barrier(0); }

// ---------------------------------------------------------------------------
// prep: cast x to bf16 + cast+transpose weights to [N][K] bf16 via LDS-tiled
// 64x64 transpose (R2).
// ---------------------------------------------------------------------------
#define XCAST_BLOCKS 1568    // NTOK*256/8/256

__device__ __forceinline__ void transpose_tile(
    const float* __restrict__ src, unsigned short* __restrict__ dst,
    int K, int N, int kt, int nt, int tid, float* lds /*64x65*/)
{
    const int k0 = kt * 64, n0 = nt * 64;
    #pragma unroll
    for (int p = 0; p < 4; ++p) {               // read 16 k-rows x 64 n each
        const int r  = p * 16 + (tid >> 4);
        const int c4 = (tid & 15) * 4;
        const float4 v = *(const float4*)(src + (size_t)(k0 + r) * N + n0 + c4);
        lds[r * 65 + c4 + 0] = v.x; lds[r * 65 + c4 + 1] = v.y;
        lds[r * 65 + c4 + 2] = v.z; lds[r * 65 + c4 + 3] = v.w;
    }
    __syncthreads();
    #pragma unroll
    for (int p = 0; p < 4; ++p) {               // write 16 n-rows x 64 k each
        const int c  = p * 16 + (tid >> 4);
        const int k4 = (tid & 15) * 4;
        ushort4 o;
        o.x = f2b(lds[(k4 + 0) * 65 + c]);
        o.y = f2b(lds[(k4 + 1) * 65 + c]);
        o.z = f2b(lds[(k4 + 2) * 65 + c]);
        o.w = f2b(lds[(k4 + 3) * 65 + c]);
        *(ushort4*)(dst + (size_t)(n0 + c) * K + k0 + k4) = o;
    }
}

__global__ __launch_bounds__(256)
void prep_kernel(const float* __restrict__ x,
                 const float* __restrict__ Wq, const float* __restrict__ Wp,
                 const float* __restrict__ W1, const float* __restrict__ W2,
                 unsigned short* __restrict__ xb,
                 unsigned short* __restrict__ Wqb, unsigned short* __restrict__ Wpb,
                 unsigned short* __restrict__ W1b, unsigned short* __restrict__ W2b)
{
    __shared__ float lds[64 * 65];
    const int tid = threadIdx.x;
    if (blockIdx.x < XCAST_BLOCKS) {
        const int i = blockIdx.x * 256 + tid;   // 8 floats each
        const float4* xp = (const float4*)x + (size_t)i * 2;
        const float4 a = xp[0], b = xp[1];
        s16x8 o;
        o[0] = (short)f2b(a.x); o[1] = (short)f2b(a.y);
        o[2] = (short)f2b(a.z); o[3] = (short)f2b(a.w);
        o[4] = (short)f2b(b.x); o[5] = (short)f2b(b.y);
        o[6] = (short)f2b(b.z); o[7] = (short)f2b(b.w);
        *((s16x8*)xb + i) = o;
        return;
    }
    int wb = blockIdx.x - XCAST_BLOCKS;
    if (wb < 48) {                 // W_qkv: K=256, N=768 -> 4x12 tiles
        transpose_tile(Wq, Wqb, 256, 768, wb & 3, wb >> 2, tid, lds);
    } else if ((wb -= 48) < 16) {  // W_proj: K=256, N=256 -> 4x4
        transpose_tile(Wp, Wpb, 256, 256, wb & 3, wb >> 2, tid, lds);
    } else if ((wb -= 16) < 64) {  // W1: K=256, N=1024 -> 4x16
        transpose_tile(W1, W1b, 256, 1024, wb & 3, wb >> 2, tid, lds);
    } else {                       // W2: K=1024, N=256 -> 16x4
        wb -= 64;
        transpose_tile(W2, W2b, 1024, 256, wb & 15, wb >> 4, tid, lds);
    }
}

// ---------------------------------------------------------------------------
// bf16 MFMA GEMM, 128x128 tile, 4 waves; XOR-swizzled LDS, XCD chunking,
// LDS-bounce epilogue (R4); counted-vmcnt pipeline (R5).
// ---------------------------------------------------------------------------
__global__ __launch_bounds__(256)
void gemm_k(const unsigned short* __restrict__ Ab,
            const unsigned short* __restrict__ Bt, const float* __restrict__ bias,
            unsigned short* __restrict__ outb,
            int N, int K, int relu)
{
    __shared__ unsigned short As[2][128 * 64];   // 32 KB (reused as Cs in epilogue)
    __shared__ unsigned short Bs[2][128 * 64];   // 32 KB

    const int tid = threadIdx.x;

    // m204 bijective XCD chunk swizzle; desired ordering d is bm-major.
    const int nwg = gridDim.x;
    const int q8 = nwg >> 3, r8 = nwg & 7;
    const int xcd = blockIdx.x & 7, pos = blockIdx.x >> 3;
    const int d = (xcd < r8 ? xcd * (q8 + 1) : r8 * (q8 + 1) + (xcd - r8) * q8) + pos;
    const int nbx = N >> 7;                      // 128-wide col tiles
    const int bm = (d / nbx) * 128, bn = (d % nbx) * 128;

    const int wid = tid >> 6, lane = tid & 63;
    const int wm = (wid >> 1) * 64, wn = (wid & 1) * 64;
    const int row16 = lane & 15, quad = lane >> 4;
    const int crow = lane >> 3;
    const int ckS = ((lane & 7) ^ crow) * 8;     // XOR-swizzled source k-block

    f32x4 acc[4][4] = {};

    auto stage = [&](int buf, int k0) {          // 8 loads per wave
        #pragma unroll
        for (int c = 0; c < 4; ++c) {
            const int ch = wid * 4 + c;
            async16(Ab + (size_t)(bm + ch * 8 + crow) * K + k0 + ckS, As[buf] + ch * 512);
        }
        #pragma unroll
        for (int c = 0; c < 4; ++c) {
            const int ch = wid * 4 + c;
            async16(Bt + (size_t)(bn + ch * 8 + crow) * K + k0 + ckS, Bs[buf] + ch * 512);
        }
    };
    auto compute = [&](int buf) {
        #pragma unroll
        for (int kc = 0; kc < 2; ++kc) {
            s16x8 af[4], bf[4];
            #pragma unroll
            for (int i = 0; i < 4; ++i)
                af[i] = *(const s16x8*)(As[buf] + (wm + i * 16 + row16) * 64
                                        + (((kc * 4 + quad) ^ (row16 & 7)) * 8));
            #pragma unroll
            for (int j = 0; j < 4; ++j)
                bf[j] = *(const s16x8*)(Bs[buf] + (wn + j * 16 + row16) * 64
                                        + (((kc * 4 + quad) ^ (row16 & 7)) * 8));
            #pragma unroll
            for (int i = 0; i < 4; ++i)
                #pragma unroll
                for (int j = 0; j < 4; ++j)
                    acc[i][j] = __builtin_amdgcn_mfma_f32_16x16x32_bf16(af[i], bf[j], acc[i][j], 0, 0, 0);
        }
    };

    stage(0, 0);
    stage(1, 64);
    const int nsteps = K >> 6;                   // 4 (K=256)
    for (int s = 0; s < nsteps; ++s) {
        const int buf = s & 1;
        if (s == nsteps - 1) WAITV(0) else WAITV(8)     // own buf's 8 loads done
        BAR()                                           // all waves' loads landed
        compute(buf);
        BAR()                                           // all waves done reading buf
        if (s + 2 < nsteps) stage(buf, (s + 2) << 6);
    }

    // ---- epilogue: bias (+relu) -> bf16 via LDS bounce, coalesced stores
    unsigned short* Cs = (unsigned short*)As;    // 128x128 bf16 = 32 KB
    #pragma unroll
    for (int j = 0; j < 4; ++j) {
        const int col = wn + j * 16 + row16;
        const float bb = bias[bn + col];
        #pragma unroll
        for (int i = 0; i < 4; ++i) {
            const int rr = wm + i * 16 + quad * 4;
            #pragma unroll
            for (int reg = 0; reg < 4; ++reg) {
                float v = acc[i][j][reg] + bb;
                if (relu) v = fmaxf(v, 0.f);
                Cs[(rr + reg) * 128 + col] = f2b(v);
            }
        }
    }
    __syncthreads();
    #pragma unroll
    for (int p = 0; p < 8; ++p) {
        const int s = p * 256 + tid;             // 2048 x 16B chunks
        const int rr = s >> 4, cb = (s & 15) * 8;
        *(s16x8*)(outb + (size_t)(bm + rr) * N + bn + cb) = *(const s16x8*)(Cs + rr * 128 + cb);
    }
}

// ---------------------------------------------------------------------------
// Fused GEMM (N=256 full-row tile) + residual add + LayerNorm.
// BM=64, 512 threads (8 waves, 2m x 4n), XOR-swizzled LDS, counted vmcnt.
// ---------------------------------------------------------------------------
__global__ __launch_bounds__(512)
void gemm_ln(const unsigned short* __restrict__ Ab, const unsigned short* __restrict__ Bt,
             const float* __restrict__ bias, const float* __restrict__ resid,
             const float* __restrict__ g, const float* __restrict__ beta,
             float* __restrict__ outf, unsigned short* __restrict__ outb, int K)
{
    __shared__ unsigned short As[2][64 * 64];    // 16 KB (buf0 reused for LN reduce)
    __shared__ unsigned short Bs[2][256 * 64];   // 64 KB

    const int tid = threadIdx.x;
    const int bm = blockIdx.x * 64;
    const int wid = tid >> 6, lane = tid & 63;
    const int wm = (wid >> 2) * 32, wn = (wid & 3) * 64;
    const int wc = wid & 3;
    const int row16 = lane & 15, quad = lane >> 4;
    const int crow = lane >> 3;
    const int ckS = ((lane & 7) ^ crow) * 8;     // XOR-swizzled source k-block

    f32x4 acc[2][4] = {};

    auto stage = [&](int buf, int k0) {          // 5 loads per wave
        #pragma unroll
        for (int c = 0; c < 5; ++c) {
            const int ch = wid * 5 + c;
            if (ch < 8) {
                async16(Ab + (size_t)(bm + ch * 8 + crow) * K + k0 + ckS, As[buf] + ch * 512);
            } else {
                const int bc = ch - 8;
                async16(Bt + (size_t)(bc * 8 + crow) * K + k0 + ckS, Bs[buf] + bc * 512);
            }
        }
    };
    auto compute = [&](int buf) {
        #pragma unroll
        for (int kc = 0; kc < 2; ++kc) {
            s16x8 af[2], bf[4];
            #pragma unroll
            for (int i = 0; i < 2; ++i)
                af[i] = *(const s16x8*)(As[buf] + (wm + i * 16 + row16) * 64
                                        + (((kc * 4 + quad) ^ (row16 & 7)) * 8));
            #pragma unroll
            for (int j = 0; j < 4; ++j)
                bf[j] = *(const s16x8*)(Bs[buf] + (wn + j * 16 + row16) * 64
                                        + (((kc * 4 + quad) ^ (row16 & 7)) * 8));
            #pragma unroll
            for (int i = 0; i < 2; ++i)
                #pragma unroll
                for (int j = 0; j < 4; ++j)
                    acc[i][j] = __builtin_amdgcn_mfma_f32_16x16x32_bf16(af[i], bf[j], acc[i][j], 0, 0, 0);
        }
    };

    stage(0, 0);
    stage(1, 64);
    const int nsteps = K >> 6;
    for (int s = 0; s < nsteps; ++s) {
        const int buf = s & 1;
        if (s == nsteps - 1) WAITV(0) else WAITV(5)
        BAR()
        compute(buf);
        BAR()
        if (s + 2 < nsteps) stage(buf, (s + 2) << 6);
    }

    // ---- epilogue: bias + residual, in-register
    float bb[4], gv[4], bev[4];
    #pragma unroll
    for (int j = 0; j < 4; ++j) {
        const int col = wn + j * 16 + row16;
        bb[j] = bias[col]; gv[j] = g[col]; bev[j] = beta[col];
    }
    #pragma unroll
    for (int i = 0; i < 2; ++i) {
        #pragma unroll
        for (int reg = 0; reg < 4; ++reg) {
            const size_t rb = (size_t)(bm + wm + i * 16 + quad * 4 + reg) * 256;
            #pragma unroll
            for (int j = 0; j < 4; ++j)
                acc[i][j][reg] += bb[j] + resid[rb + wn + j * 16 + row16];
        }
    }

    // ---- per-row sum / sumsq: reduce across row16 (16 lanes), then LDS
    float* red = (float*)As[0];           // [64 rows][4 col-waves][2]
    #pragma unroll
    for (int i = 0; i < 2; ++i) {
        #pragma unroll
        for (int reg = 0; reg < 4; ++reg) {
            float s1 = 0.f, s2 = 0.f;
            #pragma unroll
            for (int j = 0; j < 4; ++j) {
                const float t = acc[i][j][reg];
                s1 += t; s2 += t * t;
            }
            #pragma unroll
            for (int o = 1; o < 16; o <<= 1) {
                s1 += __shfl_xor(s1, o, 64);
                s2 += __shfl_xor(s2, o, 64);
            }
            if (row16 == 0) {
                const int lrow = wm + i * 16 + quad * 4 + reg;
                red[lrow * 8 + wc * 2]     = s1;
                red[lrow * 8 + wc * 2 + 1] = s2;
            }
        }
    }
    __syncthreads();
    float* stats = red + 512;             // [64][2] = m, invstd
    if (tid < 64) {
        const float S1 = red[tid*8] + red[tid*8+2] + red[tid*8+4] + red[tid*8+6];
        const float S2 = red[tid*8+1] + red[tid*8+3] + red[tid*8+5] + red[tid*8+7];
        const float m = S1 * (1.0f / 256.0f);
        const float var = S2 * (1.0f / 256.0f) - m * m;
        stats[tid * 2]     = m;
        stats[tid * 2 + 1] = rsqrtf(var + 1e-5f);
    }
    __syncthreads();

    // ---- normalize + store
    #pragma unroll
    for (int i = 0; i < 2; ++i) {
        #pragma unroll
        for (int reg = 0; reg < 4; ++reg) {
            const int lrow = wm + i * 16 + quad * 4 + reg;
            const float m = stats[lrow * 2], r = stats[lrow * 2 + 1];
            const size_t rb = (size_t)(bm + lrow) * 256;
            #pragma unroll
            for (int j = 0; j < 4; ++j) {
                const int col = wn + j * 16 + row16;
                const float o = (acc[i][j][reg] - m) * r * gv[j] + bev[j];
                outf[rb + col] = o;
                if (outb) outb[rb + col] = f2b(o);
            }
        }
    }
}

// ---------------------------------------------------------------------------
// Tiled neighborhood attention. R8: V back in LDS (R7's V-from-global cost
// +21 us: global latency in the p-dependent PV chain at 2 blocks/CU, plus
// the (256,3) bound capped VGPR at 60 and killed pipelining).
// Restructured inner loop for ILP: per halo row i, phase-split
//   (a) 7 independent QK score chains  (b) 7 independent v_exp_f32
//   (c) 7 PV accumulations with p[] known
// so exp is off the QK->PV critical path and loads pipeline 7-wide.
// log2(e) folded into the Q scale; v_exp_f32 computes 2^x directly
// (softmax invariant under base change).
// ---------------------------------------------------------------------------
__global__ __launch_bounds__(256, 2)
void natt_kernel(const unsigned short* __restrict__ qkvb, unsigned short* __restrict__ att)
{
    const int blk  = blockIdx.x;          // 4*16*8 = 512
    const int head = blk & 7;
    const int t2   = blk >> 3;
    const int tile = t2 & 15;
    const int b    = t2 >> 4;
    const int r0 = (tile >> 2) * 16, c0 = (tile & 3) * 16;
    const int hs = min(max(r0 - 3, 0), 34);
    const int ws = min(max(c0 - 3, 0), 34);

    __shared__ unsigned short Ks[NHTOK * KV_PAD];
    __shared__ unsigned short Vs[NHTOK * KV_PAD];

    const int tid = threadIdx.x;

    #pragma unroll
    for (int it = 0; it < 8; ++it) {
        const int t = it * 64 + (tid >> 2);
        if (t < NHTOK) {
            const int hr = t / HALO, hc = t - hr * HALO;
            const size_t rb = ((size_t)((b * 56 + hs + hr) * 56 + (ws + hc))) * 768;
            const int d8 = (tid & 3) * 8;
            *(s16x8*)(Ks + t * KV_PAD + d8) = *(const s16x8*)(qkvb + rb + 256 + head * 32 + d8);
            *(s16x8*)(Vs + t * KV_PAD + d8) = *(const s16x8*)(qkvb + rb + 512 + head * 32 + d8);
        }
    }

    const int qh = min(r0 + (tid >> 4), 55);
    const int qw = min(c0 + (tid & 15), 55);
    const int tok = (b * 56 + qh) * 56 + qw;
    const int ro = min(max(qh - 3, 0), 49) - hs;
    const int co = min(max(qw - 3, 0), 49) - ws;

    f32x2 qf[16];
    {
        const unsigned int* qp = (const unsigned int*)(qkvb + (size_t)tok * 768 + head * 32);
        #pragma unroll
        for (int p = 0; p < 16; ++p)
            qf[p] = unpk(qp[p]) * (0.17677669529663687f * 1.4426950408889634f);
    }
    __syncthreads();

    f32x2 acc[16] = {};
    float sum = 0.f;
    for (int i = 0; i < 7; ++i) {
        const int trow = (ro + i) * HALO + co;

        // ---- phase (a): 7 independent QK chains
        float s[7];
        #pragma unroll
        for (int j = 0; j < 7; ++j) {
            const unsigned int* kp = (const unsigned int*)(Ks + (trow + j) * KV_PAD);
            const uint4 ka = *(const uint4*)(kp);
            const uint4 kb = *(const uint4*)(kp + 4);
            const uint4 kc = *(const uint4*)(kp + 8);
            const uint4 kd = *(const uint4*)(kp + 12);
            f32x2 sa = {0.f, 0.f}, sb = {0.f, 0.f};
            sa = pk_fma(qf[0],  unpk(ka.x), sa);  sb = pk_fma(qf[1],  unpk(ka.y), sb);
            sa = pk_fma(qf[2],  unpk(ka.z), sa);  sb = pk_fma(qf[3],  unpk(ka.w), sb);
            sa = pk_fma(qf[4],  unpk(kb.x), sa);  sb = pk_fma(qf[5],  unpk(kb.y), sb);
            sa = pk_fma(qf[6],  unpk(kb.z), sa);  sb = pk_fma(qf[7],  unpk(kb.w), sb);
            sa = pk_fma(qf[8],  unpk(kc.x), sa);  sb = pk_fma(qf[9],  unpk(kc.y), sb);
            sa = pk_fma(qf[10], unpk(kc.z), sa);  sb = pk_fma(qf[11], unpk(kc.w), sb);
            sa = pk_fma(qf[12], unpk(kd.x), sa);  sb = pk_fma(qf[13], unpk(kd.y), sb);
            sa = pk_fma(qf[14], unpk(kd.z), sa);  sb = pk_fma(qf[15], unpk(kd.w), sb);
            s[j] = sa.x + sa.y + sb.x + sb.y;
        }

        // ---- phase (b): 7 independent exps (v_exp_f32 = 2^x)
        float p[7];
        #pragma unroll
        for (int j = 0; j < 7; ++j) {
            asm("v_exp_f32 %0, %1" : "=v"(p[j]) : "v"(s[j]));
        }
        #pragma unroll
        for (int j = 0; j < 7; ++j) sum += p[j];

        // ---- phase (c): 7 PV accumulations, p known
        #pragma unroll
        for (int j = 0; j < 7; ++j) {
            const unsigned int* vp = (const unsigned int*)(Vs + (trow + j) * KV_PAD);
            const uint4 va = *(const uint4*)(vp);
            const uint4 vb = *(const uint4*)(vp + 4);
            const uint4 vc = *(const uint4*)(vp + 8);
            const uint4 vd = *(const uint4*)(vp + 12);
            const f32x2 pv = {p[j], p[j]};
            acc[0]  = pk_fma(pv, unpk(va.x), acc[0]);
            acc[1]  = pk_fma(pv, unpk(va.y), acc[1]);
            acc[2]  = pk_fma(pv, unpk(va.z), acc[2]);
            acc[3]  = pk_fma(pv, unpk(va.w), acc[3]);
            acc[4]  = pk_fma(pv, unpk(vb.x), acc[4]);
            acc[5]  = pk_fma(pv, unpk(vb.y), acc[5]);
            acc[6]  = pk_fma(pv, unpk(vb.z), acc[6]);
            acc[7]  = pk_fma(pv, unpk(vb.w), acc[7]);
            acc[8]  = pk_fma(pv, unpk(vc.x), acc[8]);
            acc[9]  = pk_fma(pv, unpk(vc.y), acc[9]);
            acc[10] = pk_fma(pv, unpk(vc.z), acc[10]);
            acc[11] = pk_fma(pv, unpk(vc.w), acc[11]);
            acc[12] = pk_fma(pv, unpk(vd.x), acc[12]);
            acc[13] = pk_fma(pv, unpk(vd.y), acc[13]);
            acc[14] = pk_fma(pv, unpk(vd.z), acc[14]);
            acc[15] = pk_fma(pv, unpk(vd.w), acc[15]);
        }
    }
    const float inv = 1.0f / sum;

    unsigned short* op = att + (size_t)tok * DMODEL + head * 32;
    #pragma unroll
    for (int d4 = 0; d4 < 8; ++d4) {
        ushort4 o;
        o.x = f2b(acc[d4 * 2].x     * inv);
        o.y = f2b(acc[d4 * 2].y     * inv);
        o.z = f2b(acc[d4 * 2 + 1].x * inv);
        o.w = f2b(acc[d4 * 2 + 1].y * inv);
        *(ushort4*)(op + d4 * 4) = o;
    }
}

// ---------------------------------------------------------------------------
extern "C" void kernel_launch(void* const* d_in, const int* in_sizes, int n_in,
                              void* d_out, int out_size, void* d_ws, size_t ws_size,
                              hipStream_t stream)
{
    const float* x      = (const float*)d_in[0];
    const float* W_qkv  = (const float*)d_in[1];
    const float* b_qkv  = (const float*)d_in[2];
    const float* W_proj = (const float*)d_in[3];
    const float* b_proj = (const float*)d_in[4];
    const float* W1     = (const float*)d_in[5];
    const float* b1     = (const float*)d_in[6];
    const float* W2     = (const float*)d_in[7];
    const float* b2     = (const float*)d_in[8];
    const float* g1     = (const float*)d_in[9];
    const float* be1    = (const float*)d_in[10];
    const float* g2     = (const float*)d_in[11];
    const float* be2    = (const float*)d_in[12];
    float* out = (float*)d_out;

    char* ws = (char*)d_ws;
    const int M = NTOK;  // 12544

    unsigned short* qkvb = (unsigned short*)ws;                     // [M][768] bf16
    unsigned short* h    = (unsigned short*)ws;                     // [M][1024] bf16 (after qkvb dead)
    unsigned short* attb = (unsigned short*)(ws + 38535168);        // [M][256] bf16
    float*          xn   = (float*)(ws + 57802752);                 // [M][256] f32
    unsigned short* xnb  = (unsigned short*)(ws + 70647808);        // [M][256] bf16
    unsigned short* Wqb  = (unsigned short*)(ws + 77070336);
    unsigned short* Wpb  = Wqb + 196608;
    unsigned short* W1b  = Wpb + 65536;
    unsigned short* W2b  = W1b + 262144;
    unsigned short* xb   = (unsigned short*)(ws + 78643200);        // [M][256] bf16

    dim3 blk(256);

    // 0) cast x to bf16 + cast/transpose weights to bf16 (tiled transpose)
    prep_kernel<<<dim3(XCAST_BLOCKS + 48 + 16 + 64 + 64), blk, 0, stream>>>(
        x, W_qkv, W_proj, W1, W2, xb, Wqb, Wpb, W1b, W2b);

    // 1) qkvb = bf16(xb @ W_qkv + b_qkv)   (588 blocks, XCD-chunked)
    gemm_k<<<dim3(6 * 98), blk, 0, stream>>>(xb, Wqb, b_qkv, qkvb, 768, 256, 0);

    // 2) tiled neighborhood attention -> attb
    natt_kernel<<<dim3(512), blk, 0, stream>>>(qkvb, attb);

    // 3+4) xn = LN(x + attb @ W_proj + b_proj)  (f32 + bf16), fused
    gemm_ln<<<dim3(M / 64), dim3(512), 0, stream>>>(attb, Wpb, b_proj, x, g1, be1, xn, xnb, 256);

    // 5) h = relu(xnb @ W1 + b1)  (bf16, 784 blocks, XCD-chunked)
    gemm_k<<<dim3(8 * 98), blk, 0, stream>>>(xnb, W1b, b1, h, 1024, 256, 1);

    // 6+7) out = LN(xn + h @ W2 + b2), fused
    gemm_ln<<<dim3(M / 64), dim3(512), 0, stream>>>(h, W2b, b2, xn, g2, be2, out, nullptr, 1024);
}

// Round 10
// 164.522 us; speedup vs baseline: 1.1892x; 1.0653x over previous
//
#include <hip/hip_runtime.h>
#include <math.h>

// Problem constants
#define BATCH 4
#define HH 56
#define WW 56
#define DMODEL 256
#define NHEADS 8
#define HD 32
#define NNB 49               // 7x7 neighborhood
#define NTOK (BATCH*HH*WW)   // 12544

#define HALO 22              // 16 + 2*3
#define NHTOK (HALO*HALO)    // 484

typedef __attribute__((ext_vector_type(8))) short s16x8;
typedef __attribute__((ext_vector_type(4))) float f32x4;

__device__ inline unsigned short f2b(float f) {
    union { float f; unsigned int u; } v; v.f = f;
    unsigned int r = v.u + 0x7FFF + ((v.u >> 16) & 1);  // RNE
    return (unsigned short)(r >> 16);
}
__device__ inline float b2f(unsigned short u) {
    union { float f; unsigned int u; } v; v.u = ((unsigned int)u) << 16;
    return v.f;
}

// async 16B/lane global->LDS copy; lds base wave-uniform, lane i -> base+i*16
__device__ __forceinline__ void async16(const unsigned short* g, unsigned short* l) {
    __builtin_amdgcn_global_load_lds(
        (const __attribute__((address_space(1))) unsigned int*)g,
        (__attribute__((address_space(3))) unsigned int*)l, 16, 0, 0);
}

// counted-vmcnt fences (T4). Memory clobber keeps LDS reads from hoisting
// above the wait; sched_barrier pins the boundary (rule #18).
#define WAITV(N) { asm volatile("s_waitcnt vmcnt(" #N ")" ::: "memory"); }
#define BAR()    { __builtin_amdgcn_s_barrier(); __builtin_amdgcn_sched_barrier(0); }

// ---------------------------------------------------------------------------
// prep: cast x to bf16 + cast+transpose weights to [N][K] bf16 via LDS-tiled
// 64x64 transpose (R2).
// ---------------------------------------------------------------------------
#define XCAST_BLOCKS 1568    // NTOK*256/8/256

__device__ __forceinline__ void transpose_tile(
    const float* __restrict__ src, unsigned short* __restrict__ dst,
    int K, int N, int kt, int nt, int tid, float* lds /*64x65*/)
{
    const int k0 = kt * 64, n0 = nt * 64;
    #pragma unroll
    for (int p = 0; p < 4; ++p) {               // read 16 k-rows x 64 n each
        const int r  = p * 16 + (tid >> 4);
        const int c4 = (tid & 15) * 4;
        const float4 v = *(const float4*)(src + (size_t)(k0 + r) * N + n0 + c4);
        lds[r * 65 + c4 + 0] = v.x; lds[r * 65 + c4 + 1] = v.y;
        lds[r * 65 + c4 + 2] = v.z; lds[r * 65 + c4 + 3] = v.w;
    }
    __syncthreads();
    #pragma unroll
    for (int p = 0; p < 4; ++p) {               // write 16 n-rows x 64 k each
        const int c  = p * 16 + (tid >> 4);
        const int k4 = (tid & 15) * 4;
        ushort4 o;
        o.x = f2b(lds[(k4 + 0) * 65 + c]);
        o.y = f2b(lds[(k4 + 1) * 65 + c]);
        o.z = f2b(lds[(k4 + 2) * 65 + c]);
        o.w = f2b(lds[(k4 + 3) * 65 + c]);
        *(ushort4*)(dst + (size_t)(n0 + c) * K + k0 + k4) = o;
    }
}

__global__ __launch_bounds__(256)
void prep_kernel(const float* __restrict__ x,
                 const float* __restrict__ Wq, const float* __restrict__ Wp,
                 const float* __restrict__ W1, const float* __restrict__ W2,
                 unsigned short* __restrict__ xb,
                 unsigned short* __restrict__ Wqb, unsigned short* __restrict__ Wpb,
                 unsigned short* __restrict__ W1b, unsigned short* __restrict__ W2b)
{
    __shared__ float lds[64 * 65];
    const int tid = threadIdx.x;
    if (blockIdx.x < XCAST_BLOCKS) {
        const int i = blockIdx.x * 256 + tid;   // 8 floats each
        const float4* xp = (const float4*)x + (size_t)i * 2;
        const float4 a = xp[0], b = xp[1];
        s16x8 o;
        o[0] = (short)f2b(a.x); o[1] = (short)f2b(a.y);
        o[2] = (short)f2b(a.z); o[3] = (short)f2b(a.w);
        o[4] = (short)f2b(b.x); o[5] = (short)f2b(b.y);
        o[6] = (short)f2b(b.z); o[7] = (short)f2b(b.w);
        *((s16x8*)xb + i) = o;
        return;
    }
    int wb = blockIdx.x - XCAST_BLOCKS;
    if (wb < 48) {                 // W_qkv: K=256, N=768 -> 4x12 tiles
        transpose_tile(Wq, Wqb, 256, 768, wb & 3, wb >> 2, tid, lds);
    } else if ((wb -= 48) < 16) {  // W_proj: K=256, N=256 -> 4x4
        transpose_tile(Wp, Wpb, 256, 256, wb & 3, wb >> 2, tid, lds);
    } else if ((wb -= 16) < 64) {  // W1: K=256, N=1024 -> 4x16
        transpose_tile(W1, W1b, 256, 1024, wb & 3, wb >> 2, tid, lds);
    } else {                       // W2: K=1024, N=256 -> 16x4
        wb -= 64;
        transpose_tile(W2, W2b, 1024, 256, wb & 15, wb >> 4, tid, lds);
    }
}

// ---------------------------------------------------------------------------
// bf16 MFMA GEMM, 128x128 tile, 4 waves; XOR-swizzled LDS, XCD chunking,
// LDS-bounce epilogue (R4); counted-vmcnt pipeline (R5).
// ---------------------------------------------------------------------------
__global__ __launch_bounds__(256)
void gemm_k(const unsigned short* __restrict__ Ab,
            const unsigned short* __restrict__ Bt, const float* __restrict__ bias,
            unsigned short* __restrict__ outb,
            int N, int K, int relu)
{
    __shared__ unsigned short As[2][128 * 64];   // 32 KB (reused as Cs in epilogue)
    __shared__ unsigned short Bs[2][128 * 64];   // 32 KB

    const int tid = threadIdx.x;

    // m204 bijective XCD chunk swizzle; desired ordering d is bm-major.
    const int nwg = gridDim.x;
    const int q8 = nwg >> 3, r8 = nwg & 7;
    const int xcd = blockIdx.x & 7, pos = blockIdx.x >> 3;
    const int d = (xcd < r8 ? xcd * (q8 + 1) : r8 * (q8 + 1) + (xcd - r8) * q8) + pos;
    const int nbx = N >> 7;                      // 128-wide col tiles
    const int bm = (d / nbx) * 128, bn = (d % nbx) * 128;

    const int wid = tid >> 6, lane = tid & 63;
    const int wm = (wid >> 1) * 64, wn = (wid & 1) * 64;
    const int row16 = lane & 15, quad = lane >> 4;
    const int crow = lane >> 3;
    const int ckS = ((lane & 7) ^ crow) * 8;     // XOR-swizzled source k-block

    f32x4 acc[4][4] = {};

    auto stage = [&](int buf, int k0) {          // 8 loads per wave
        #pragma unroll
        for (int c = 0; c < 4; ++c) {
            const int ch = wid * 4 + c;
            async16(Ab + (size_t)(bm + ch * 8 + crow) * K + k0 + ckS, As[buf] + ch * 512);
        }
        #pragma unroll
        for (int c = 0; c < 4; ++c) {
            const int ch = wid * 4 + c;
            async16(Bt + (size_t)(bn + ch * 8 + crow) * K + k0 + ckS, Bs[buf] + ch * 512);
        }
    };
    auto compute = [&](int buf) {
        #pragma unroll
        for (int kc = 0; kc < 2; ++kc) {
            s16x8 af[4], bf[4];
            #pragma unroll
            for (int i = 0; i < 4; ++i)
                af[i] = *(const s16x8*)(As[buf] + (wm + i * 16 + row16) * 64
                                        + (((kc * 4 + quad) ^ (row16 & 7)) * 8));
            #pragma unroll
            for (int j = 0; j < 4; ++j)
                bf[j] = *(const s16x8*)(Bs[buf] + (wn + j * 16 + row16) * 64
                                        + (((kc * 4 + quad) ^ (row16 & 7)) * 8));
            #pragma unroll
            for (int i = 0; i < 4; ++i)
                #pragma unroll
                for (int j = 0; j < 4; ++j)
                    acc[i][j] = __builtin_amdgcn_mfma_f32_16x16x32_bf16(af[i], bf[j], acc[i][j], 0, 0, 0);
        }
    };

    stage(0, 0);
    stage(1, 64);
    const int nsteps = K >> 6;                   // 4 (K=256)
    for (int s = 0; s < nsteps; ++s) {
        const int buf = s & 1;
        if (s == nsteps - 1) WAITV(0) else WAITV(8)     // own buf's 8 loads done
        BAR()                                           // all waves' loads landed
        compute(buf);
        BAR()                                           // all waves done reading buf
        if (s + 2 < nsteps) stage(buf, (s + 2) << 6);
    }

    // ---- epilogue: bias (+relu) -> bf16 via LDS bounce, coalesced stores
    unsigned short* Cs = (unsigned short*)As;    // 128x128 bf16 = 32 KB
    #pragma unroll
    for (int j = 0; j < 4; ++j) {
        const int col = wn + j * 16 + row16;
        const float bb = bias[bn + col];
        #pragma unroll
        for (int i = 0; i < 4; ++i) {
            const int rr = wm + i * 16 + quad * 4;
            #pragma unroll
            for (int reg = 0; reg < 4; ++reg) {
                float v = acc[i][j][reg] + bb;
                if (relu) v = fmaxf(v, 0.f);
                Cs[(rr + reg) * 128 + col] = f2b(v);
            }
        }
    }
    __syncthreads();
    #pragma unroll
    for (int p = 0; p < 8; ++p) {
        const int s = p * 256 + tid;             // 2048 x 16B chunks
        const int rr = s >> 4, cb = (s & 15) * 8;
        *(s16x8*)(outb + (size_t)(bm + rr) * N + bn + cb) = *(const s16x8*)(Cs + rr * 128 + cb);
    }
}

// ---------------------------------------------------------------------------
// Fused GEMM (N=256 full-row tile) + residual add + LayerNorm.
// BM=64, 512 threads (8 waves, 2m x 4n), XOR-swizzled LDS, counted vmcnt.
// ---------------------------------------------------------------------------
__global__ __launch_bounds__(512)
void gemm_ln(const unsigned short* __restrict__ Ab, const unsigned short* __restrict__ Bt,
             const float* __restrict__ bias, const float* __restrict__ resid,
             const float* __restrict__ g, const float* __restrict__ beta,
             float* __restrict__ outf, unsigned short* __restrict__ outb, int K)
{
    __shared__ unsigned short As[2][64 * 64];    // 16 KB (buf0 reused for LN reduce)
    __shared__ unsigned short Bs[2][256 * 64];   // 64 KB

    const int tid = threadIdx.x;
    const int bm = blockIdx.x * 64;
    const int wid = tid >> 6, lane = tid & 63;
    const int wm = (wid >> 2) * 32, wn = (wid & 3) * 64;
    const int wc = wid & 3;
    const int row16 = lane & 15, quad = lane >> 4;
    const int crow = lane >> 3;
    const int ckS = ((lane & 7) ^ crow) * 8;     // XOR-swizzled source k-block

    f32x4 acc[2][4] = {};

    auto stage = [&](int buf, int k0) {          // 5 loads per wave
        #pragma unroll
        for (int c = 0; c < 5; ++c) {
            const int ch = wid * 5 + c;
            if (ch < 8) {
                async16(Ab + (size_t)(bm + ch * 8 + crow) * K + k0 + ckS, As[buf] + ch * 512);
            } else {
                const int bc = ch - 8;
                async16(Bt + (size_t)(bc * 8 + crow) * K + k0 + ckS, Bs[buf] + bc * 512);
            }
        }
    };
    auto compute = [&](int buf) {
        #pragma unroll
        for (int kc = 0; kc < 2; ++kc) {
            s16x8 af[2], bf[4];
            #pragma unroll
            for (int i = 0; i < 2; ++i)
                af[i] = *(const s16x8*)(As[buf] + (wm + i * 16 + row16) * 64
                                        + (((kc * 4 + quad) ^ (row16 & 7)) * 8));
            #pragma unroll
            for (int j = 0; j < 4; ++j)
                bf[j] = *(const s16x8*)(Bs[buf] + (wn + j * 16 + row16) * 64
                                        + (((kc * 4 + quad) ^ (row16 & 7)) * 8));
            #pragma unroll
            for (int i = 0; i < 2; ++i)
                #pragma unroll
                for (int j = 0; j < 4; ++j)
                    acc[i][j] = __builtin_amdgcn_mfma_f32_16x16x32_bf16(af[i], bf[j], acc[i][j], 0, 0, 0);
        }
    };

    stage(0, 0);
    stage(1, 64);
    const int nsteps = K >> 6;
    for (int s = 0; s < nsteps; ++s) {
        const int buf = s & 1;
        if (s == nsteps - 1) WAITV(0) else WAITV(5)
        BAR()
        compute(buf);
        BAR()
        if (s + 2 < nsteps) stage(buf, (s + 2) << 6);
    }

    // ---- epilogue: bias + residual, in-register
    float bb[4], gv[4], bev[4];
    #pragma unroll
    for (int j = 0; j < 4; ++j) {
        const int col = wn + j * 16 + row16;
        bb[j] = bias[col]; gv[j] = g[col]; bev[j] = beta[col];
    }
    #pragma unroll
    for (int i = 0; i < 2; ++i) {
        #pragma unroll
        for (int reg = 0; reg < 4; ++reg) {
            const size_t rb = (size_t)(bm + wm + i * 16 + quad * 4 + reg) * 256;
            #pragma unroll
            for (int j = 0; j < 4; ++j)
                acc[i][j][reg] += bb[j] + resid[rb + wn + j * 16 + row16];
        }
    }

    // ---- per-row sum / sumsq: reduce across row16 (16 lanes), then LDS
    float* red = (float*)As[0];           // [64 rows][4 col-waves][2]
    #pragma unroll
    for (int i = 0; i < 2; ++i) {
        #pragma unroll
        for (int reg = 0; reg < 4; ++reg) {
            float s1 = 0.f, s2 = 0.f;
            #pragma unroll
            for (int j = 0; j < 4; ++j) {
                const float t = acc[i][j][reg];
                s1 += t; s2 += t * t;
            }
            #pragma unroll
            for (int o = 1; o < 16; o <<= 1) {
                s1 += __shfl_xor(s1, o, 64);
                s2 += __shfl_xor(s2, o, 64);
            }
            if (row16 == 0) {
                const int lrow = wm + i * 16 + quad * 4 + reg;
                red[lrow * 8 + wc * 2]     = s1;
                red[lrow * 8 + wc * 2 + 1] = s2;
            }
        }
    }
    __syncthreads();
    float* stats = red + 512;             // [64][2] = m, invstd
    if (tid < 64) {
        const float S1 = red[tid*8] + red[tid*8+2] + red[tid*8+4] + red[tid*8+6];
        const float S2 = red[tid*8+1] + red[tid*8+3] + red[tid*8+5] + red[tid*8+7];
        const float m = S1 * (1.0f / 256.0f);
        const float var = S2 * (1.0f / 256.0f) - m * m;
        stats[tid * 2]     = m;
        stats[tid * 2 + 1] = rsqrtf(var + 1e-5f);
    }
    __syncthreads();

    // ---- normalize + store
    #pragma unroll
    for (int i = 0; i < 2; ++i) {
        #pragma unroll
        for (int reg = 0; reg < 4; ++reg) {
            const int lrow = wm + i * 16 + quad * 4 + reg;
            const float m = stats[lrow * 2], r = stats[lrow * 2 + 1];
            const size_t rb = (size_t)(bm + lrow) * 256;
            #pragma unroll
            for (int j = 0; j < 4; ++j) {
                const int col = wn + j * 16 + row16;
                const float o = (acc[i][j][reg] - m) * r * gv[j] + bev[j];
                outf[rb + col] = o;
                if (outb) outb[rb + col] = f2b(o);
            }
        }
    }
}

// ---------------------------------------------------------------------------
// R10: MFMA neighborhood attention (R9 + pad-zeroing NaN fix).
// Per block: 16x16 query tile, 1 head, 4 waves; each wave owns 4 query rows.
// Dense S[16q][22c] per (query-row, halo-row) with window masking.
// NaN fix: the PV MFMA computes sum_k P[q][k]*V[k][d] in HARDWARE — masked
// P=0 entries still multiply V, so uninitialized V pads (possible NaN bf16
// patterns) gave 0*NaN=NaN. Zero all never-staged pad regions:
//   Ks: hc=22,23 rows + 8-row tail (read by kb at l15>=6 / hi=21)
//   Vt: cols 22,23 of every row + 64-short tail (read by quad 2/3 B-frags)
// Pads are disjoint from staged regions -> no extra barrier needed.
// ---------------------------------------------------------------------------
__global__ __launch_bounds__(256, 2)
void natt_kernel(const unsigned short* __restrict__ qkvb, unsigned short* __restrict__ att)
{
    const int blk  = blockIdx.x;          // 4*16*8 = 512
    const int head = blk & 7;
    const int t2   = blk >> 3;
    const int tile = t2 & 15;
    const int b    = t2 >> 4;
    const int r0 = (tile >> 2) * 16, c0 = (tile & 3) * 16;
    const int hs = min(max(r0 - 3, 0), 34);
    const int ws = min(max(c0 - 3, 0), 34);

    __shared__ __attribute__((aligned(16))) unsigned short Ks[(22*24 + 8) * 32]; // 34304 B
    __shared__ __attribute__((aligned(16))) unsigned short Vt[22*32*24 + 64];    // 33920 B
    __shared__ __attribute__((aligned(16))) unsigned short Ps[4 * 2 * 16 * 32];  //  8192 B

    const int tid = threadIdx.x;
    const int wid = tid >> 6, lane = tid & 63;
    const int l15 = lane & 15, quad = lane >> 4;
    unsigned short* Psw = Ps + wid * 1024;       // per-wave 2KB (2 buffers)

    // ---- zero never-staged pads (NaN fix; disjoint from staged regions)
    const s16x8 zz = {};
    for (int t = tid; t < 44; t += 256) {        // Ks pad cols hc=22,23
        const int hr = t >> 1, hc = 22 + (t & 1);
        #pragma unroll
        for (int d8 = 0; d8 < 32; d8 += 8)
            *(s16x8*)(Ks + (hr*24 + hc)*32 + d8) = zz;
    }
    if (tid < 32)                                // Ks 8-row tail (rows 528..535)
        *(s16x8*)(Ks + (528 + (tid >> 2))*32 + (tid & 3)*8) = zz;
    for (int t = tid; t < 704; t += 256)         // Vt pad cols 22,23 (1 u32/row)
        *(unsigned int*)(Vt + t*24 + 22) = 0u;
    if (tid < 8)                                 // Vt 64-short tail
        *(s16x8*)(Vt + 22*32*24 + tid*8) = zz;

    // ---- stage K: 484 tokens x 32d, 4 threads/token, row stride 24 tokens
    #pragma unroll
    for (int it = 0; it < 8; ++it) {
        const int t = it * 64 + (tid >> 2);
        if (t < NHTOK) {
            const int hr = t / HALO, hc = t - hr * HALO;
            const size_t rb = ((size_t)((b*56 + hs + hr)*56 + (ws + hc))) * 768;
            const int d8 = (tid & 3) * 8;
            *(s16x8*)(Ks + (hr*24 + hc)*32 + d8) =
                *(const s16x8*)(qkvb + rb + 256 + head*32 + d8);
        }
    }
    // ---- stage V transposed: one thread per token PAIR (hc even, hc+1)
    if (tid < 242) {
        const int hr = tid / 11, ph = tid - hr * 11, hc = ph * 2;
        const size_t rb0 = ((size_t)((b*56 + hs + hr)*56 + (ws + hc))) * 768 + 512 + head*32;
        unsigned int wa[16], wb[16];
        #pragma unroll
        for (int k = 0; k < 4; ++k) {
            *(uint4*)(wa + k*4) = *(const uint4*)((const unsigned int*)(qkvb + rb0) + k*4);
            *(uint4*)(wb + k*4) = *(const uint4*)((const unsigned int*)(qkvb + rb0 + 768) + k*4);
        }
        #pragma unroll
        for (int d = 0; d < 32; ++d) {
            const unsigned int a  = (wa[d>>1] >> ((d&1)*16)) & 0xffffu;
            const unsigned int bv = (wb[d>>1] >> ((d&1)*16)) & 0xffffu;
            *(unsigned int*)(Vt + (hr*32 + d)*24 + hc) = a | (bv << 16);
        }
    }

    // ---- per-wave query-row setup: Q B-frags in registers, row windows
    s16x8 qf[4];
    int rs[4];
    #pragma unroll
    for (int r = 0; r < 4; ++r) {
        const int qh = min(r0 + wid*4 + r, 55);
        rs[r] = min(max(qh - 3, 0), 49) - hs;            // wave-uniform
        const int qw = min(c0 + l15, 55);
        qf[r] = *(const s16x8*)(qkvb + (size_t)((b*56+qh)*56+qw)*768 + head*32 + quad*8);
    }
    const int qwl = min(c0 + l15, 55);
    const int cs = min(max(qwl - 3, 0), 49) - ws;        // col-window start (halo coords)
    __syncthreads();

    f32x4 out[4][2] = {};        // [qrow r][d-half]
    float ssum[4] = {};
    const float SCL = 0.17677669529663687f * 1.4426950408889634f;   // /sqrt(32) * log2(e)
    const int rsmin = min(min(rs[0], rs[1]), min(rs[2], rs[3]));
    const int rsmax = max(max(rs[0], rs[1]), max(rs[2], rs[3]));

    auto qk_phase = [&](int r, int bufo, const s16x8& ka, const s16x8& kb) {
        const f32x4 z = {0.f, 0.f, 0.f, 0.f};
        f32x4 s0 = __builtin_amdgcn_mfma_f32_16x16x32_bf16(ka, qf[r], z, 0, 0, 0);
        f32x4 s1 = __builtin_amdgcn_mfma_f32_16x16x32_bf16(kb, qf[r], z, 0, 0, 0);
        float p0[4], p1[4];
        #pragma unroll
        for (int j = 0; j < 4; ++j) {
            float e0, e1;
            asm("v_exp_f32 %0, %1" : "=v"(e0) : "v"(s0[j] * SCL));
            asm("v_exp_f32 %0, %1" : "=v"(e1) : "v"(s1[j] * SCL));
            const int c0i = quad*4 + j;                   // this reg's halo col (frag0)
            p0[j] = ((unsigned)(c0i - cs)      < 7u) ? e0 : 0.f;
            p1[j] = ((unsigned)(c0i + 16 - cs) < 7u) ? e1 : 0.f;
            ssum[r] += p0[j] + p1[j];
        }
        unsigned int u00, u01, u10, u11;
        asm("v_cvt_pk_bf16_f32 %0, %1, %2" : "=v"(u00) : "v"(p0[0]), "v"(p0[1]));
        asm("v_cvt_pk_bf16_f32 %0, %1, %2" : "=v"(u01) : "v"(p0[2]), "v"(p0[3]));
        asm("v_cvt_pk_bf16_f32 %0, %1, %2" : "=v"(u10) : "v"(p1[0]), "v"(p1[1]));
        asm("v_cvt_pk_bf16_f32 %0, %1, %2" : "=v"(u11) : "v"(p1[2]), "v"(p1[3]));
        uint2 w0; w0.x = u00; w0.y = u01;
        uint2 w1; w1.x = u10; w1.y = u11;
        // P^T[c][q]: lane holds q=l15, c = {quad*4+j} and {16+quad*4+j}
        // -> Ps[q][c] row-major so the A-frag read below is lane-exact.
        *(uint2*)(Psw + bufo + l15*32 + quad*4)      = w0;
        *(uint2*)(Psw + bufo + l15*32 + 16 + quad*4) = w1;
    };
    auto pv_phase = [&](int r, int bufo, const s16x8& v0, const s16x8& v1) {
        s16x8 pf = *(const s16x8*)(Psw + bufo + l15*32 + quad*8);   // A: row q=l15, k=quad*8+e
        out[r][0] = __builtin_amdgcn_mfma_f32_16x16x32_bf16(pf, v0, out[r][0], 0, 0, 0);
        out[r][1] = __builtin_amdgcn_mfma_f32_16x16x32_bf16(pf, v1, out[r][1], 0, 0, 0);
    };

    for (int hi = rsmin; hi <= rsmax + 6; ++hi) {
        // K A-frags (c-halves m=0,1): row c=m*16+l15, k d=quad*8+e
        const s16x8 ka = *(const s16x8*)(Ks + (hi*24 + l15)*32 + quad*8);
        const s16x8 kb = *(const s16x8*)(Ks + (hi*24 + 16 + l15)*32 + quad*8);
        // V B-frags (d-halves n=0,1): col d=n*16+l15, k c=quad*8+e
        const s16x8 v0 = *(const s16x8*)(Vt + (hi*32 + l15)*24 + quad*8);
        const s16x8 v1 = *(const s16x8*)(Vt + (hi*32 + 16 + l15)*24 + quad*8);
        #pragma unroll
        for (int rp = 0; rp < 2; ++rp) {
            const int ra = rp*2, rb_ = rp*2 + 1;
            const bool Aa = (unsigned)(hi - rs[ra])  < 7u;   // wave-uniform
            const bool Ab = (unsigned)(hi - rs[rb_]) < 7u;
            if (Aa) qk_phase(ra, 0, ka, kb);
            if (Ab) qk_phase(rb_, 512, ka, kb);
            if (Aa || Ab) {
                asm volatile("s_waitcnt lgkmcnt(0)" ::: "memory");
                __builtin_amdgcn_sched_barrier(0);
            }
            if (Aa) pv_phase(ra, 0, v0, v1);
            if (Ab) pv_phase(rb_, 512, v0, v1);
        }
    }

    // ---- normalize + store (per qrow): sum over quads, LDS-bounce store
    float invs[4];
    #pragma unroll
    for (int r = 0; r < 4; ++r) {
        float s = ssum[r];
        s += __shfl_xor(s, 16, 64);
        s += __shfl_xor(s, 32, 64);
        invs[r] = 1.0f / s;                      // valid at all lanes for q=l15
    }
    unsigned short* Csw = Psw;                   // reuse wave-private region
    #pragma unroll
    for (int r = 0; r < 4; ++r) {
        asm volatile("s_waitcnt lgkmcnt(0)" ::: "memory");
        __builtin_amdgcn_sched_barrier(0);
        #pragma unroll
        for (int reg = 0; reg < 4; ++reg) {
            const float iv = __shfl(invs[r], quad*4 + reg, 64);
            // out C layout: row q = quad*4+reg, col d = l15 (+16 for half 1)
            Csw[(quad*4+reg)*32 + l15]      = f2b(out[r][0][reg] * iv);
            Csw[(quad*4+reg)*32 + 16 + l15] = f2b(out[r][1][reg] * iv);
        }
        asm volatile("s_waitcnt lgkmcnt(0)" ::: "memory");
        __builtin_amdgcn_sched_barrier(0);
        const int qc = lane >> 2, ch = lane & 3;
        const int qh = min(r0 + wid*4 + r, 55);
        const int qw = min(c0 + qc, 55);
        *(s16x8*)(att + (size_t)((b*56+qh)*56+qw)*256 + head*32 + ch*8) =
            *(const s16x8*)(Csw + qc*32 + ch*8);
    }
}

// ---------------------------------------------------------------------------
extern "C" void kernel_launch(void* const* d_in, const int* in_sizes, int n_in,
                              void* d_out, int out_size, void* d_ws, size_t ws_size,
                              hipStream_t stream)
{
    const float* x      = (const float*)d_in[0];
    const float* W_qkv  = (const float*)d_in[1];
    const float* b_qkv  = (const float*)d_in[2];
    const float* W_proj = (const float*)d_in[3];
    const float* b_proj = (const float*)d_in[4];
    const float* W1     = (const float*)d_in[5];
    const float* b1     = (const float*)d_in[6];
    const float* W2     = (const float*)d_in[7];
    const float* b2     = (const float*)d_in[8];
    const float* g1     = (const float*)d_in[9];
    const float* be1    = (const float*)d_in[10];
    const float* g2     = (const float*)d_in[11];
    const float* be2    = (const float*)d_in[12];
    float* out = (float*)d_out;

    char* ws = (char*)d_ws;
    const int M = NTOK;  // 12544

    unsigned short* qkvb = (unsigned short*)ws;                     // [M][768] bf16
    unsigned short* h    = (unsigned short*)ws;                     // [M][1024] bf16 (after qkvb dead)
    unsigned short* attb = (unsigned short*)(ws + 38535168);        // [M][256] bf16
    float*          xn   = (float*)(ws + 57802752);                 // [M][256] f32
    unsigned short* xnb  = (unsigned short*)(ws + 70647808);        // [M][256] bf16
    unsigned short* Wqb  = (unsigned short*)(ws + 77070336);
    unsigned short* Wpb  = Wqb + 196608;
    unsigned short* W1b  = Wpb + 65536;
    unsigned short* W2b  = W1b + 262144;
    unsigned short* xb   = (unsigned short*)(ws + 78643200);        // [M][256] bf16

    dim3 blk(256);

    // 0) cast x to bf16 + cast/transpose weights to bf16 (tiled transpose)
    prep_kernel<<<dim3(XCAST_BLOCKS + 48 + 16 + 64 + 64), blk, 0, stream>>>(
        x, W_qkv, W_proj, W1, W2, xb, Wqb, Wpb, W1b, W2b);

    // 1) qkvb = bf16(xb @ W_qkv + b_qkv)   (588 blocks, XCD-chunked)
    gemm_k<<<dim3(6 * 98), blk, 0, stream>>>(xb, Wqb, b_qkv, qkvb, 768, 256, 0);

    // 2) MFMA tiled neighborhood attention -> attb
    natt_kernel<<<dim3(512), blk, 0, stream>>>(qkvb, attb);

    // 3+4) xn = LN(x + attb @ W_proj + b_proj)  (f32 + bf16), fused
    gemm_ln<<<dim3(M / 64), dim3(512), 0, stream>>>(attb, Wpb, b_proj, x, g1, be1, xn, xnb, 256);

    // 5) h = relu(xnb @ W1 + b1)  (bf16, 784 blocks, XCD-chunked)
    gemm_k<<<dim3(8 * 98), blk, 0, stream>>>(xnb, W1b, b1, h, 1024, 256, 1);

    // 6+7) out = LN(xn + h @ W2 + b2), fused
    gemm_ln<<<dim3(M / 64), dim3(512), 0, stream>>>(h, W2b, b2, xn, g2, be2, out, nullptr, 1024);
}